// Round 1
// baseline (267.085 us; speedup 1.0000x reference)
//
#include <hip/hip_runtime.h>
#include <hip/hip_cooperative_groups.h>
#include <math.h>

namespace cg = cooperative_groups;

#define B_ 64
#define S_ 512
#define N_ 24
#define H_ 768
#define C_ 6
#define OUT_ELEMS (B_ * N_ * C_)  // 9216

// ---------------- fused cooperative kernel ----------------
// 512 blocks (2/CU co-resident) x 256 threads. Each block: 64 tokens of one
// batch. Wave handles 16 contiguous tokens in two 8-token prefetch halves.
// Cross-block reduction goes through d_out itself (atomicAdd) with two
// grid.sync()s: zero -> accumulate -> finalize in place. No workspace.
#define FCH 8                 // chunks (blocks) per batch
#define FTOK (S_ / FCH)       // 64 tokens per block
#define FTOKW (FTOK / 4)      // 16 tokens per wave
#define FGRID (B_ * FCH)      // 512 blocks

__global__ __launch_bounds__(256, 2) void fused_kernel(
    const float* __restrict__ lhs, const int* __restrict__ st,
    const float* __restrict__ W, const float* __restrict__ bias,
    float* __restrict__ out) {
  __shared__ float acc[N_ * C_ * 64];  // 36 KB
  const int tid = threadIdx.x;
  const int lane = tid & 63;
  const int wave = tid >> 6;
  const int b = blockIdx.x >> 3;
  const int chunk = blockIdx.x & 7;
  const int flat = blockIdx.x * 256 + tid;

  // Phase A: zero the output accumulator via RMW so the zeros live at the
  // device coherence point the phase-B atomicAdds operate on (cross-XCD safe).
  if (flat < OUT_ELEMS) atomicExch(&out[flat], 0.0f);

  // zero LDS accumulators (2304 float4s / 256 threads = 9 each)
  float4* accv = (float4*)acc;
#pragma unroll
  for (int i = 0; i < 9; ++i)
    accv[i * 256 + tid] = make_float4(0.f, 0.f, 0.f, 0.f);

  // boundaries resident in lanes (sentinel for lanes >= 24)
  int stb_l = (lane < N_) ? st[b * N_ + lane] : 0x7fffffff;

  // W fragment: lane holds W[c][k*256 + lane*4 .. +3], k=0..2, c=0..5 (72 VGPRs)
  const float4* W4 = (const float4*)W;
  float4 w[3][C_];
#pragma unroll
  for (int k = 0; k < 3; ++k)
#pragma unroll
    for (int c = 0; c < C_; ++c)
      w[k][c] = W4[c * (H_ / 4) + k * 64 + lane];
  // pin: forbid rematerialization of the W loads
#pragma unroll
  for (int k = 0; k < 3; ++k)
    asm volatile("" : "+v"(w[k][0].x), "+v"(w[k][0].y), "+v"(w[k][0].z), "+v"(w[k][0].w),
                       "+v"(w[k][1].x), "+v"(w[k][1].y), "+v"(w[k][1].z), "+v"(w[k][1].w),
                       "+v"(w[k][2].x), "+v"(w[k][2].y), "+v"(w[k][2].z), "+v"(w[k][2].w),
                       "+v"(w[k][3].x), "+v"(w[k][3].y), "+v"(w[k][3].z), "+v"(w[k][3].w),
                       "+v"(w[k][4].x), "+v"(w[k][4].y), "+v"(w[k][4].z), "+v"(w[k][4].w),
                       "+v"(w[k][5].x), "+v"(w[k][5].y), "+v"(w[k][5].z), "+v"(w[k][5].w));

  __syncthreads();

  const int s_base = chunk * FTOK + wave * FTOKW;
  const float4* x4 = (const float4*)(lhs + ((size_t)b * S_ + s_base) * H_);

  float racc[C_] = {0.f, 0.f, 0.f, 0.f, 0.f, 0.f};
  int cur_seg = N_;  // sentinel: nothing pending
#pragma unroll 1     // do NOT unroll: x[8][3] + w[3][6] must fit in 256 VGPRs
  for (int h = 0; h < 2; ++h) {
    // prefetch 8 tokens (24 independent 1-KiB wave loads in flight)
    float4 x[8][3];
#pragma unroll
    for (int t = 0; t < 8; ++t) {
      const int tt = h * 8 + t;
      x[t][0] = x4[tt * 192 + lane];
      x[t][1] = x4[tt * 192 + 64 + lane];
      x[t][2] = x4[tt * 192 + 128 + lane];
    }
#pragma unroll
    for (int t = 0; t < 8; ++t) {
      const int s = s_base + h * 8 + t;
      // segment id = count of boundaries < s (wave-uniform)
      const int seg = (int)__popcll(__ballot(stb_l < s));
      if (seg != cur_seg) {  // rare: ~1-2 times per wave
        if (cur_seg < N_) {
#pragma unroll
          for (int c = 0; c < C_; ++c)
            atomicAdd(&acc[(cur_seg * C_ + c) * 64 + lane], racc[c]);
        }
#pragma unroll
        for (int c = 0; c < C_; ++c) racc[c] = 0.f;
        cur_seg = seg;
      }
      // tokens past the last boundary have seg==24; never flushed -> ignored
#pragma unroll
      for (int k = 0; k < 3; ++k)
#pragma unroll
        for (int c = 0; c < C_; ++c)
          racc[c] += x[t][k].x * w[k][c].x + x[t][k].y * w[k][c].y +
                     x[t][k].z * w[k][c].z + x[t][k].w * w[k][c].w;
    }
  }
  if (cur_seg < N_) {
#pragma unroll
    for (int c = 0; c < C_; ++c)
      atomicAdd(&acc[(cur_seg * C_ + c) * 64 + lane], racc[c]);
  }

  __syncthreads();

  // block reduce: 144 threads each sum 64 lane-partials (skewed: conflict-free)
  float v = 0.f;
  if (tid < N_ * C_) {
    const int base = tid * 64;
#pragma unroll 8
    for (int i = 0; i < 64; ++i) v += acc[base + ((i + tid) & 63)];
  }

  cg::this_grid().sync();  // all zeros landed at the coherence point

  if (tid < N_ * C_) atomicAdd(&out[b * N_ * C_ + tid], v);

  cg::this_grid().sync();  // all partials landed

  // Phase C: finalize in place
  if (flat < OUT_ELEMS) {
    const float ssum = atomicAdd(&out[flat], 0.0f);  // coherent RMW read
    const int c = flat % C_;
    const int j = (flat / C_) % N_;
    const int bb = flat / (N_ * C_);
    const int end = st[bb * N_ + j];
    const int prev = (j == 0) ? -1 : st[bb * N_ + j - 1];
    const float logit = ssum / (float)(end - prev) + bias[c];
    float p = 1.0f / (1.0f + expf(-logit));
    if (end > 500) {
      const float cl = (c < 3) ? 0.1f : (c == 3 ? 0.3f : (c == 4 ? 0.8f : 0.01f));
      const float cm = (c < 3) ? 0.1f : (c == 3 ? 0.8f : (c == 4 ? 0.3f : 0.01f));
      p = (j == N_ - 1) ? cl : cm;
    }
    out[flat] = p;
  }
}

// ---------------- fallback: previous two-kernel path ----------------
#define OCH 16                      // blocks per batch
#define OTB (S_ / OCH)              // 32 tokens per block
#define OTW (OTB / 4)               // 8 tokens per wave

__global__ __launch_bounds__(256, 2) void seg_proj_kernel(
    const float* __restrict__ lhs, const int* __restrict__ st,
    const float* __restrict__ W, float* __restrict__ outbuf, int use_atomic) {
  __shared__ float acc[N_ * C_ * 64];
  const int tid = threadIdx.x;
  const int lane = tid & 63;
  const int wave = tid >> 6;
  const int b = blockIdx.x / OCH;
  const int chunk = blockIdx.x % OCH;

  float4* accv = (float4*)acc;
#pragma unroll
  for (int i = 0; i < 9; ++i)
    accv[i * 256 + tid] = make_float4(0.f, 0.f, 0.f, 0.f);

  int stb_l = (lane < N_) ? st[b * N_ + lane] : 0x7fffffff;

  const float4* W4 = (const float4*)W;
  float4 w[3][C_];
#pragma unroll
  for (int k = 0; k < 3; ++k)
#pragma unroll
    for (int c = 0; c < C_; ++c)
      w[k][c] = W4[c * (H_ / 4) + k * 64 + lane];
#pragma unroll
  for (int k = 0; k < 3; ++k)
    asm volatile("" : "+v"(w[k][0].x), "+v"(w[k][0].y), "+v"(w[k][0].z), "+v"(w[k][0].w),
                       "+v"(w[k][1].x), "+v"(w[k][1].y), "+v"(w[k][1].z), "+v"(w[k][1].w),
                       "+v"(w[k][2].x), "+v"(w[k][2].y), "+v"(w[k][2].z), "+v"(w[k][2].w),
                       "+v"(w[k][3].x), "+v"(w[k][3].y), "+v"(w[k][3].z), "+v"(w[k][3].w),
                       "+v"(w[k][4].x), "+v"(w[k][4].y), "+v"(w[k][4].z), "+v"(w[k][4].w),
                       "+v"(w[k][5].x), "+v"(w[k][5].y), "+v"(w[k][5].z), "+v"(w[k][5].w));

  __syncthreads();

  const int s_base = chunk * OTB + wave * OTW;
  const float4* x4 = (const float4*)(lhs + ((size_t)b * S_ + s_base) * H_);
  float4 x[OTW][3];
#pragma unroll
  for (int t = 0; t < OTW; ++t) {
    x[t][0] = x4[t * 192 + lane];
    x[t][1] = x4[t * 192 + 64 + lane];
    x[t][2] = x4[t * 192 + 128 + lane];
  }

  float racc[C_] = {0.f, 0.f, 0.f, 0.f, 0.f, 0.f};
  int cur_seg = N_;
#pragma unroll
  for (int t = 0; t < OTW; ++t) {
    const int s = s_base + t;
    const int seg = (int)__popcll(__ballot(stb_l < s));
    if (seg != cur_seg) {
      if (cur_seg < N_) {
#pragma unroll
        for (int c = 0; c < C_; ++c)
          atomicAdd(&acc[(cur_seg * C_ + c) * 64 + lane], racc[c]);
      }
#pragma unroll
      for (int c = 0; c < C_; ++c) racc[c] = 0.f;
      cur_seg = seg;
    }
#pragma unroll
    for (int k = 0; k < 3; ++k)
#pragma unroll
      for (int c = 0; c < C_; ++c)
        racc[c] += x[t][k].x * w[k][c].x + x[t][k].y * w[k][c].y +
                   x[t][k].z * w[k][c].z + x[t][k].w * w[k][c].w;
  }
  if (cur_seg < N_) {
#pragma unroll
    for (int c = 0; c < C_; ++c)
      atomicAdd(&acc[(cur_seg * C_ + c) * 64 + lane], racc[c]);
  }

  __syncthreads();
  if (tid < N_ * C_) {
    float v = 0.f;
    const int base = tid * 64;
#pragma unroll 8
    for (int i = 0; i < 64; ++i) v += acc[base + ((i + tid) & 63)];
    if (use_atomic)
      atomicAdd(&outbuf[b * N_ * C_ + tid], v);
    else
      outbuf[(size_t)blockIdx.x * (N_ * C_) + tid] = v;
  }
}

__global__ __launch_bounds__(256) void finalize_kernel(
    const float* __restrict__ buf, const int* __restrict__ st,
    const float* __restrict__ bias, float* __restrict__ out, int use_atomic) {
  int idx = blockIdx.x * blockDim.x + threadIdx.x;
  if (idx >= B_ * N_ * C_) return;
  int c = idx % C_;
  int j = (idx / C_) % N_;
  int b = idx / (N_ * C_);
  float ssum;
  if (use_atomic) {
    ssum = buf[idx];
  } else {
    ssum = 0.f;
#pragma unroll
    for (int k = 0; k < OCH; ++k)
      ssum += buf[(size_t)(b * OCH + k) * (N_ * C_) + j * C_ + c];
  }
  int end = st[b * N_ + j];
  int prev = (j == 0) ? -1 : st[b * N_ + j - 1];
  float len = (float)(end - prev);
  float logit = ssum / len + bias[c];
  float p = 1.0f / (1.0f + expf(-logit));
  if (end > 500) {
    float cl = (c < 3) ? 0.1f : (c == 3 ? 0.3f : (c == 4 ? 0.8f : 0.01f));
    float cm = (c < 3) ? 0.1f : (c == 3 ? 0.8f : (c == 4 ? 0.3f : 0.01f));
    p = (j == N_ - 1) ? cl : cm;
  }
  out[idx] = p;
}

extern "C" void kernel_launch(void* const* d_in, const int* in_sizes, int n_in,
                              void* d_out, int out_size, void* d_ws, size_t ws_size,
                              hipStream_t stream) {
  const float* lhs  = (const float*)d_in[0];  // [B,S,H] fp32
  const int*   st   = (const int*)d_in[1];    // [B,N] int32
  const float* W    = (const float*)d_in[2];  // [C,H] fp32
  const float* bias = (const float*)d_in[3];  // [C] fp32
  float* out = (float*)d_out;

  void* args[] = {(void*)&lhs, (void*)&st, (void*)&W, (void*)&bias, (void*)&out};
  hipError_t e = hipLaunchCooperativeKernel((const void*)fused_kernel, dim3(FGRID),
                                            dim3(256), (void**)args, 0, stream);
  if (e != hipSuccess) {
    // fallback: proven two-kernel path through the workspace
    const size_t need = (size_t)B_ * OCH * N_ * C_ * sizeof(float);  // 576 KB
    const int use_atomic = (ws_size < need) ? 1 : 0;
    if (use_atomic)
      hipMemsetAsync(d_ws, 0, (size_t)B_ * N_ * C_ * sizeof(float), stream);
    seg_proj_kernel<<<B_ * OCH, 256, 0, stream>>>(lhs, st, W, (float*)d_ws, use_atomic);
    finalize_kernel<<<(B_ * N_ * C_ + 255) / 256, 256, 0, stream>>>(
        (float*)d_ws, st, bias, out, use_atomic);
  }
}